// Round 1
// baseline (137.483 us; speedup 1.0000x reference)
//
#include <hip/hip_runtime.h>
#include <hip/hip_bf16.h>

typedef short s16x8 __attribute__((ext_vector_type(8)));
typedef float f32x16 __attribute__((ext_vector_type(16)));

#define LOG2E 1.44269504088896f

__device__ __forceinline__ unsigned bfpack2(float lo, float hi) {
  unsigned a = (unsigned)__builtin_bit_cast(unsigned short, __float2bfloat16(lo));
  unsigned b = (unsigned)__builtin_bit_cast(unsigned short, __float2bfloat16(hi));
  return a | (b << 16);
}

union U4 { unsigned u[4]; uint4 q; s16x8 v; };

// B=2,H=16,S=2048,D=128. QBLK=128 (4 waves x 32 q-rows), KVBLK=64.
// Swapped QK^T and swapped PV: scores and O both carry q on lane&31,
// so online-softmax state (m, l, corr) is entirely lane-local.
__global__ __launch_bounds__(256, 2)
void attn_alibi(const float* __restrict__ Qg, const float* __restrict__ Kg,
                const float* __restrict__ Vg, float* __restrict__ Og) {
  constexpr int S = 2048, Dh = 128;

  // block decode: XCD-grouped (all q-tiles of a head share an XCD's L2),
  // heavy-first within head for causal load balance
  const int lid  = (int)blockIdx.x;
  const int xcd  = lid & 7;
  const int slot = lid >> 3;
  const int bh   = xcd + 8 * (slot >> 4);   // 0..31
  const int qt   = 15 - (slot & 15);        // heavy tiles first
  const int head = bh & 15;

  const size_t base = (size_t)bh * S * Dh;
  const float* qp = Qg + base;
  const float* kp = Kg + base;
  const float* vp = Vg + base;

  const int tid  = (int)threadIdx.x;
  const int wq   = tid >> 6;     // wave id: q sub-tile
  const int lane = tid & 63;
  const int l31  = lane & 31;
  const int h5   = lane >> 5;

  const int q0   = qt << 7;
  const int iq   = q0 + 32 * wq + l31;   // this lane's q row
  const int qmax = q0 + 32 * wq + 31;    // wave's max q row

  const float c1     = 0.08838834764831845f * LOG2E;          // log2e/sqrt(128)
  const float slope2 = exp2f(-0.5f * (float)(head + 1)) * LOG2E; // alibi slope in log2 units

  __shared__ __align__(16) char smem[16384 + 18432];
  char* smK = smem;           // K tile bf16 [64][128], 256B rows, XOR-swizzled
  char* smV = smem + 16384;   // V^T tile bf16 [128][72] (stride 144B, padded)

  // Q fragments (B operand of S^T): elem i <-> d = 16*ks + 8*h5 + i
  s16x8 qf[8];
  {
    const float* qrow = qp + (size_t)iq * Dh;
    #pragma unroll
    for (int ks = 0; ks < 8; ++ks) {
      const float* p = qrow + 16 * ks + 8 * h5;
      float4 a = *(const float4*)p;
      float4 b = *(const float4*)(p + 4);
      U4 w;
      w.u[0] = bfpack2(a.x, a.y);
      w.u[1] = bfpack2(a.z, a.w);
      w.u[2] = bfpack2(b.x, b.y);
      w.u[3] = bfpack2(b.z, b.w);
      qf[ks] = w.v;
    }
  }

  f32x16 oacc[4];
  #pragma unroll
  for (int dt = 0; dt < 4; ++dt)
    #pragma unroll
    for (int r = 0; r < 16; ++r) oacc[dt][r] = 0.0f;

  float m2 = -1e30f, lsum = 0.0f;

  // staging decomposition
  const int kvr = tid >> 2;        // K: row 0..63, 4 threads/row
  const int kcb = tid & 3;         // K: 8-elem chunk base
  const int kvp = (tid >> 3) << 1; // V: even kv row of the pair
  const int vdb = (tid & 7) << 2;  // V: d base

  const int nt = 2 * (qt + 1);     // causal: kv tiles 0..nt-1
  for (int t = 0; t < nt; ++t) {
    const int kv0 = t << 6;
    __syncthreads();
    // ---- stage K -> bf16 LDS, XOR-swizzled 16B granules (conflict-free) ----
    {
      const float* krow = kp + (size_t)(kv0 + kvr) * Dh;
      #pragma unroll
      for (int p = 0; p < 4; ++p) {
        const int c = kcb + 4 * p;          // 8-elem chunk 0..15
        const float* src = krow + 8 * c;
        float4 a = *(const float4*)src;
        float4 b = *(const float4*)(src + 4);
        U4 w;
        w.u[0] = bfpack2(a.x, a.y);
        w.u[1] = bfpack2(a.z, a.w);
        w.u[2] = bfpack2(b.x, b.y);
        w.u[3] = bfpack2(b.z, b.w);
        *(uint4*)(smK + kvr * 256 + ((c * 16) ^ ((kvr & 7) << 4))) = w.q;
      }
    }
    // ---- stage V^T -> bf16 LDS [128][72], packed b32 writes ----
    {
      const float* v0 = vp + (size_t)(kv0 + kvp) * Dh;
      const float* v1 = v0 + Dh;
      #pragma unroll
      for (int p = 0; p < 4; ++p) {
        const int d0 = vdb + 32 * p;
        float4 a = *(const float4*)(v0 + d0);
        float4 b = *(const float4*)(v1 + d0);
        *(unsigned*)(smV + (d0 + 0) * 144 + kvp * 2) = bfpack2(a.x, b.x);
        *(unsigned*)(smV + (d0 + 1) * 144 + kvp * 2) = bfpack2(a.y, b.y);
        *(unsigned*)(smV + (d0 + 2) * 144 + kvp * 2) = bfpack2(a.z, b.z);
        *(unsigned*)(smV + (d0 + 3) * 144 + kvp * 2) = bfpack2(a.w, b.w);
      }
    }
    __syncthreads();
    if (kv0 > qmax) continue;   // tile fully above diagonal for this wave

    // ---- S^T = K · Q^T : C col = q = l31, row = kv pattern ----
    f32x16 sc[2];
    #pragma unroll
    for (int kt = 0; kt < 2; ++kt) {
      #pragma unroll
      for (int r = 0; r < 16; ++r) sc[kt][r] = 0.0f;
      const int row   = kt * 32 + l31;
      const int rbase = row * 256;
      const int swz   = (row & 7) << 4;
      #pragma unroll
      for (int ks = 0; ks < 8; ++ks) {
        s16x8 a = *(const s16x8*)(smK + rbase + ((32 * ks + 16 * h5) ^ swz));
        sc[kt] = __builtin_amdgcn_mfma_f32_32x32x16_bf16(a, qf[ks], sc[kt], 0, 0, 0);
      }
    }

    // ---- online softmax: lane owns one q, 32 kv values in-register ----
    float mloc = -1e30f;
    #pragma unroll
    for (int kt = 0; kt < 2; ++kt) {
      #pragma unroll
      for (int r = 0; r < 16; ++r) {
        const float pat = (float)((r & 3) + 8 * (r >> 2) + 4 * h5 + 32 * kt);
        const float dj  = (float)(kv0 - iq) + pat;       // j - i
        float v = fmaf(sc[kt][r], c1, slope2 * dj);      // scaled dot + alibi (log2 domain)
        v = (dj > 0.0f) ? -1e30f : v;                    // causal mask
        sc[kt][r] = v;
        mloc = fmaxf(mloc, v);
      }
    }
    mloc = fmaxf(mloc, __shfl_xor(mloc, 32));
    const float mnew = fmaxf(m2, mloc);
    const float corr = exp2f(m2 - mnew);
    m2 = mnew;
    float ps = 0.0f;
    #pragma unroll
    for (int kt = 0; kt < 2; ++kt)
      #pragma unroll
      for (int r = 0; r < 16; ++r) {
        const float pv = exp2f(sc[kt][r] - mnew);
        sc[kt][r] = pv;
        ps += pv;
      }
    ps += __shfl_xor(ps, 32);
    lsum = lsum * corr + ps;
    #pragma unroll
    for (int dt = 0; dt < 4; ++dt)
      #pragma unroll
      for (int r = 0; r < 16; ++r) oacc[dt][r] *= corr;

    // ---- pack P^T: pk[kt][rg][j] = bf16 pair kv (8rg + 4*h5 + 2j, +1) ----
    unsigned pk[2][4][2];
    #pragma unroll
    for (int kt = 0; kt < 2; ++kt)
      #pragma unroll
      for (int rg = 0; rg < 4; ++rg) {
        pk[kt][rg][0] = bfpack2(sc[kt][4 * rg + 0], sc[kt][4 * rg + 1]);
        pk[kt][rg][1] = bfpack2(sc[kt][4 * rg + 2], sc[kt][4 * rg + 3]);
      }

    // ---- O^T += V^T · P^T  (half-exchange builds P^T B-fragments) ----
    #pragma unroll
    for (int ks = 0; ks < 4; ++ks) {
      const int kt = ks >> 1;
      const int x  = 2 * (ks & 1);
      const unsigned own0 = h5 ? pk[kt][x + 1][0] : pk[kt][x][0];
      const unsigned own1 = h5 ? pk[kt][x + 1][1] : pk[kt][x][1];
      const unsigned snd0 = h5 ? pk[kt][x][0]     : pk[kt][x + 1][0];
      const unsigned snd1 = h5 ? pk[kt][x][1]     : pk[kt][x + 1][1];
      const unsigned sh0 = (unsigned)__shfl_xor((int)snd0, 32);
      const unsigned sh1 = (unsigned)__shfl_xor((int)snd1, 32);
      U4 bfr;
      bfr.u[0] = h5 ? sh0 : own0;
      bfr.u[1] = h5 ? sh1 : own1;
      bfr.u[2] = h5 ? own0 : sh0;
      bfr.u[3] = h5 ? own1 : sh1;
      const int voff = (16 * ks + 8 * h5) * 2;
      #pragma unroll
      for (int dt = 0; dt < 4; ++dt) {
        s16x8 a = *(const s16x8*)(smV + (32 * dt + l31) * 144 + voff);
        oacc[dt] = __builtin_amdgcn_mfma_f32_32x32x16_bf16(a, bfr.v, oacc[dt], 0, 0, 0);
      }
    }
  }

  // ---- epilogue: O^T regs hold col=q (lane-local l), rows = d pattern ----
  const float rl = 1.0f / lsum;
  float* orow = Og + base + (size_t)iq * Dh;
  #pragma unroll
  for (int dt = 0; dt < 4; ++dt)
    #pragma unroll
    for (int rg = 0; rg < 4; ++rg) {
      float4 v;
      v.x = oacc[dt][4 * rg + 0] * rl;
      v.y = oacc[dt][4 * rg + 1] * rl;
      v.z = oacc[dt][4 * rg + 2] * rl;
      v.w = oacc[dt][4 * rg + 3] * rl;
      *(float4*)(orow + 32 * dt + 8 * rg + 4 * h5) = v;
    }
}

extern "C" void kernel_launch(void* const* d_in, const int* in_sizes, int n_in,
                              void* d_out, int out_size, void* d_ws, size_t ws_size,
                              hipStream_t stream) {
  (void)in_sizes; (void)n_in; (void)d_ws; (void)ws_size; (void)out_size;
  const float* q = (const float*)d_in[0];
  const float* k = (const float*)d_in[1];
  const float* v = (const float*)d_in[2];
  float* o = (float*)d_out;
  attn_alibi<<<dim3(512), dim3(256), 0, stream>>>(q, k, v, o);
}